// Round 6
// baseline (1097.869 us; speedup 1.0000x reference)
//
#include <hip/hip_runtime.h>

typedef __attribute__((ext_vector_type(8))) short short8;
typedef __attribute__((ext_vector_type(16))) float f32x16;

#define MFMA32 __builtin_amdgcn_mfma_f32_32x32x16_bf16

__device__ __forceinline__ unsigned short f2bf(float f) {
  unsigned int u = __float_as_uint(f);
  u += 0x7fffu + ((u >> 16) & 1u);
  return (unsigned short)(u >> 16);
}

// Pre-pack the 6 weight matrices fp32 [k][n] -> bf16 MFMA-fragment order:
// wt[(((s*6 + g)*8 + c)*64 + l)*8 + j] = G_g[k][n]
//   with k = s*16 + (l>>5)*8 + j, n = c*32 + (l&31)
// One (slab,gate,chunk) brick = 1 KB = one wave's B-fragment, contiguous.
__global__ __launch_bounds__(256) void wprep(
    const float* __restrict__ Wu, const float* __restrict__ Wr, const float* __restrict__ Wh,
    const float* __restrict__ Uu, const float* __restrict__ Ur, const float* __restrict__ Uh,
    unsigned short* __restrict__ wt) {
  int idx = blockIdx.x * 256 + threadIdx.x;   // 0 .. 6*65536-1
  int j = idx & 7;
  int l = (idx >> 3) & 63;
  int c = (idx >> 9) & 7;
  int sg = idx >> 12;
  int g = sg % 6;
  int s = sg / 6;
  int k = s * 16 + (l >> 5) * 8 + j;
  int n = c * 32 + (l & 31);
  const float* src = (g == 0) ? Wu : (g == 1) ? Wr : (g == 2) ? Wh
                   : (g == 3) ? Uu : (g == 4) ? Ur : Uh;
  wt[idx] = f2bf(src[k * 256 + n]);
}

// Fused AUGRU. Block = 512 thr (8 waves), tile 64 rows x 256 cols.
// Wave w owns cols [32w, 32w+32), all 64 rows, mfma 32x32x16.
// Weights: global->VGPR ring, depth 4 slabs. No barriers in K-loops.
// ONE shared 32KB tile buffer: x-pass reads it, then h overwrites it.
__global__ __launch_bounds__(512, 4) void augru_main(
    const float* __restrict__ x, const float* __restrict__ h1,
    const float* __restrict__ a, const unsigned short* __restrict__ wt,
    const float* __restrict__ bu, const float* __restrict__ br,
    const float* __restrict__ bh, float* __restrict__ out) {
  __shared__ char lT[32768];     // tile buffer: x then h (bf16, swizzled)
  __shared__ float a_s[64];

  const int tid = threadIdx.x;
  const int l   = tid & 63;
  const int wid = tid >> 6;          // 0..7 -> 32-col chunk
  const int fr  = l & 31;            // row (A) / col (B,C)
  const int fq  = l >> 5;            // k-half (A/B) / row+4 group (C)
  const long rowbase = (long)blockIdx.x * 64;
  const int aswz = (fr & 7) << 4;
  const int n = wid * 32 + fr;

  const char* wb = (const char*)wt + (wid << 10) + (l << 4);
#define WOFF(SG) ((SG) << 13)

  // ---- issue x tile loads (all 8 up front: max MLP) ----
  const float* xsrc = x + rowbase * 256;
  float4 xv[8];
#pragma unroll
  for (int i = 0; i < 8; ++i) xv[i] = ((const float4*)xsrc)[i * 512 + tid];

  // ---- prefetch W ring: x-gate slabs 0..3 ----
  short8 W[4][3];
#pragma unroll
  for (int i = 0; i < 4; ++i)
#pragma unroll
    for (int g = 0; g < 3; ++g)
      W[i][g] = *(const short8*)(wb + WOFF(i * 6 + g));

  // ---- issue first half of h tile loads ----
  const float* hsrc = h1 + rowbase * 256;
  float4 hv[8];
#pragma unroll
  for (int i = 0; i < 4; ++i) hv[i] = ((const float4*)hsrc)[i * 512 + tid];

  const float vbu = bu[n], vbr = br[n], vbh = bh[n];
  if (tid < 64) a_s[tid] = a[rowbase + tid];

  // ---- convert + write x tile (swizzled: byte ^= (row&7)<<4) ----
#pragma unroll
  for (int i = 0; i < 8; ++i) {
    int f   = i * 512 + tid;
    int row = f >> 6;
    int kq  = f & 63;
    ushort4 b;
    b.x = f2bf(xv[i].x); b.y = f2bf(xv[i].y); b.z = f2bf(xv[i].z); b.w = f2bf(xv[i].w);
    *(ushort4*)(lT + (row << 9) + ((kq * 8) ^ ((row & 7) << 4))) = b;
  }
  __syncthreads();   // x tile ready

  f32x16 accU0 = {}, accU1 = {};
  f32x16 accR0 = {}, accR1 = {};
  f32x16 accXH0 = {}, accXH1 = {};
  f32x16 accHH0 = {}, accHH1 = {};

  // ---- x-pass: slabs 0..15, gates 0-2 (Wu,Wr,Wh). No barriers. ----
#pragma unroll
  for (int s = 0; s < 16; ++s) {
    const int koff = ((s << 5) + (fq << 4)) ^ aswz;
    short8 ax0 = *(const short8*)(lT + (fr << 9) + koff);
    short8 ax1 = *(const short8*)(lT + ((fr + 32) << 9) + koff);
    __builtin_amdgcn_s_setprio(1);
    accU0  = MFMA32(ax0, W[s & 3][0], accU0, 0, 0, 0);
    accU1  = MFMA32(ax1, W[s & 3][0], accU1, 0, 0, 0);
    accR0  = MFMA32(ax0, W[s & 3][1], accR0, 0, 0, 0);
    accR1  = MFMA32(ax1, W[s & 3][1], accR1, 0, 0, 0);
    accXH0 = MFMA32(ax0, W[s & 3][2], accXH0, 0, 0, 0);
    accXH1 = MFMA32(ax1, W[s & 3][2], accXH1, 0, 0, 0);
    __builtin_amdgcn_s_setprio(0);
    // refill ring set (s&3): 4 slabs ahead; roll into h-gate slabs 0..3
    const int sg = (s + 4 < 16) ? (s + 4) * 6 : (s - 12) * 6 + 3;
#pragma unroll
    for (int g = 0; g < 3; ++g)
      W[s & 3][g] = *(const short8*)(wb + WOFF(sg + g));
    if (s == 4) {
#pragma unroll
      for (int i = 4; i < 8; ++i) hv[i] = ((const float4*)hsrc)[i * 512 + tid];
    }
  }
  __syncthreads();   // all x-pass reads of lT done

  // ---- overwrite tile with h (from registers) ----
#pragma unroll
  for (int i = 0; i < 8; ++i) {
    int f   = i * 512 + tid;
    int row = f >> 6;
    int kq  = f & 63;
    ushort4 b;
    b.x = f2bf(hv[i].x); b.y = f2bf(hv[i].y); b.z = f2bf(hv[i].z); b.w = f2bf(hv[i].w);
    *(ushort4*)(lT + (row << 9) + ((kq * 8) ^ ((row & 7) << 4))) = b;
  }
  __syncthreads();   // h tile ready

  // ---- h-pass: slabs 0..15, gates 3-5 (Uu,Ur,Uh). No barriers. ----
#pragma unroll
  for (int s = 0; s < 16; ++s) {
    const int koff = ((s << 5) + (fq << 4)) ^ aswz;
    short8 ah0 = *(const short8*)(lT + (fr << 9) + koff);
    short8 ah1 = *(const short8*)(lT + ((fr + 32) << 9) + koff);
    __builtin_amdgcn_s_setprio(1);
    accU0  = MFMA32(ah0, W[s & 3][0], accU0, 0, 0, 0);
    accU1  = MFMA32(ah1, W[s & 3][0], accU1, 0, 0, 0);
    accR0  = MFMA32(ah0, W[s & 3][1], accR0, 0, 0, 0);
    accR1  = MFMA32(ah1, W[s & 3][1], accR1, 0, 0, 0);
    accHH0 = MFMA32(ah0, W[s & 3][2], accHH0, 0, 0, 0);
    accHH1 = MFMA32(ah1, W[s & 3][2], accHH1, 0, 0, 0);
    __builtin_amdgcn_s_setprio(0);
    if (s + 4 < 16) {
      const int sg = (s + 4) * 6 + 3;
#pragma unroll
      for (int g = 0; g < 3; ++g)
        W[s & 3][g] = *(const short8*)(wb + WOFF(sg + g));
    }
  }

  // ---- epilogue: coalesced fp32 h1 re-read (L2/L3-hot), light gate math ----
  const float* hcol = h1 + rowbase * 256 + n;
  float* ocol = out + rowbase * 256 + n;
  float hE0[16], hE1[16];
#pragma unroll
  for (int g8 = 0; g8 < 4; ++g8)
#pragma unroll
    for (int j = 0; j < 4; ++j) {
      const int rl = g8 * 8 + fq * 4 + j;
      hE0[g8 * 4 + j] = hcol[(long)rl * 256];
      hE1[g8 * 4 + j] = hcol[(long)(rl + 32) * 256];
    }

#define EPI(ACCU, ACCR, ACCXH, ACCHH, HE, RB)                               \
  _Pragma("unroll")                                                         \
  for (int g8 = 0; g8 < 4; ++g8) {                                          \
    _Pragma("unroll")                                                       \
    for (int j = 0; j < 4; ++j) {                                           \
      const int reg = g8 * 4 + j;                                           \
      const int rl  = (RB) + g8 * 8 + fq * 4 + j;                           \
      const float pu = ACCU[reg] + vbu;                                     \
      const float pr = ACCR[reg] + vbr;                                     \
      const float uu = __builtin_amdgcn_rcpf(1.f + __expf(-pu));            \
      const float rr = __builtin_amdgcn_rcpf(1.f + __expf(-pr));            \
      const float cc = fmaf(rr, ACCHH[reg], ACCXH[reg]) + vbh;              \
      const float tt = __builtin_amdgcn_rcpf(1.f + __expf(-2.f * cc));      \
      const float th = fmaf(2.f, tt, -1.f);                                 \
      const float uh = a_s[rl] * uu;                                        \
      const float h1v = HE[reg];                                            \
      ocol[(long)rl * 256] = fmaf(uh, th - h1v, h1v);                       \
    }                                                                       \
  }

  EPI(accU0, accR0, accXH0, accHH0, hE0, 0)
  EPI(accU1, accR1, accXH1, accHH1, hE1, 32)
#undef EPI
#undef WOFF
}

extern "C" void kernel_launch(void* const* d_in, const int* in_sizes, int n_in,
                              void* d_out, int out_size, void* d_ws, size_t ws_size,
                              hipStream_t stream) {
  const float* x  = (const float*)d_in[0];
  const float* h1 = (const float*)d_in[1];
  const float* a  = (const float*)d_in[2];
  const float* Wu = (const float*)d_in[3];
  const float* Uu = (const float*)d_in[4];
  const float* bu = (const float*)d_in[5];
  const float* Wr = (const float*)d_in[6];
  const float* Ur = (const float*)d_in[7];
  const float* br = (const float*)d_in[8];
  const float* Wh = (const float*)d_in[9];
  const float* Uh = (const float*)d_in[10];
  const float* bh = (const float*)d_in[11];
  unsigned short* wt = (unsigned short*)d_ws;   // 16 slabs x 48 KB = 768 KB

  wprep<<<1536, 256, 0, stream>>>(Wu, Wr, Wh, Uu, Ur, Uh, wt);

  const int rows = in_sizes[0] / 256;           // 65536
  augru_main<<<rows / 64, 512, 0, stream>>>(x, h1, a, wt, bu, br, bh,
                                            (float*)d_out);
}

// Round 7
// 98.587 us; speedup vs baseline: 11.1361x; 11.1361x over previous
//
#include <hip/hip_runtime.h>

typedef __attribute__((ext_vector_type(8))) short short8;
typedef __attribute__((ext_vector_type(16))) float f32x16;

#define MFMA32 __builtin_amdgcn_mfma_f32_32x32x16_bf16

__device__ __forceinline__ unsigned short f2bf(float f) {
  unsigned int u = __float_as_uint(f);
  u += 0x7fffu + ((u >> 16) & 1u);
  return (unsigned short)(u >> 16);
}

// Pre-pack the 6 weight matrices fp32 [k][n] -> bf16 MFMA-fragment order:
// wt[(((s*6 + g)*8 + c)*64 + l)*8 + j] = G_g[k][n]
//   with k = s*16 + (l>>5)*8 + j, n = c*32 + (l&31)
// One (slab,gate,chunk) brick = 1 KB = one wave's B-fragment, contiguous.
__global__ __launch_bounds__(256) void wprep(
    const float* __restrict__ Wu, const float* __restrict__ Wr, const float* __restrict__ Wh,
    const float* __restrict__ Uu, const float* __restrict__ Ur, const float* __restrict__ Uh,
    unsigned short* __restrict__ wt) {
  int idx = blockIdx.x * 256 + threadIdx.x;   // 0 .. 6*65536-1
  int j = idx & 7;
  int l = (idx >> 3) & 63;
  int c = (idx >> 9) & 7;
  int sg = idx >> 12;
  int g = sg % 6;
  int s = sg / 6;
  int k = s * 16 + (l >> 5) * 8 + j;
  int n = c * 32 + (l & 31);
  const float* src = (g == 0) ? Wu : (g == 1) ? Wr : (g == 2) ? Wh
                   : (g == 3) ? Uu : (g == 4) ? Ur : Uh;
  wt[idx] = f2bf(src[k * 256 + n]);
}

// Fused AUGRU. Block = 256 thr (4 waves), tile 32 rows x 128 cols.
// bid>>1 = row stripe, bid&1 = col half. Wave w owns cols chunk=(bid&1)*4+w.
// acc = 4 x f32x16 = 64 AGPR. W ring depth 3 in VGPRs. One barrier.
// x/h tiles in LDS in MFMA-fragment order: lane l of slab s reads 16B at
// (s<<10) + ((l^(s&7))<<4)  -> conflict-free ds_read_b128.
__global__ __launch_bounds__(256, 3) void augru_main(
    const float* __restrict__ x, const float* __restrict__ h1,
    const float* __restrict__ a, const unsigned short* __restrict__ wt,
    const float* __restrict__ bu, const float* __restrict__ br,
    const float* __restrict__ bh, float* __restrict__ out) {
  __shared__ char lX[16384];     // x tile, fragment-order bf16
  __shared__ char lH[16384];     // h tile, fragment-order bf16
  __shared__ float a_s[32];

  const int tid  = threadIdx.x;
  const int l    = tid & 63;
  const int widc = tid >> 6;           // 0..3
  const int fq   = l >> 5;             // k-half (A/B); +4 row group (C)
  const int bid  = blockIdx.x;
  const long rowbase = (long)(bid >> 1) * 32;
  const int chunk = (bid & 1) * 4 + widc;      // 0..7
  const int n = chunk * 32 + (l & 31);

  const char* wb = (const char*)wt + (chunk << 10) + (l << 4);
#define WOFF(SG) ((SG) << 13)

  // ---- issue x + h tile loads (32KB each, 8 float4/thread) ----
  const float* xsrc = x + rowbase * 256;
  const float* hsrc = h1 + rowbase * 256;
  float4 xv[8], hv[8];
#pragma unroll
  for (int i = 0; i < 8; ++i) xv[i] = ((const float4*)xsrc)[i * 256 + tid];
#pragma unroll
  for (int i = 0; i < 8; ++i) hv[i] = ((const float4*)hsrc)[i * 256 + tid];

  // ---- prefetch W ring: slabs 0..2, all 6 gates ----
  short8 W[3][6];
#pragma unroll
  for (int i = 0; i < 3; ++i)
#pragma unroll
    for (int g = 0; g < 6; ++g)
      W[i][g] = *(const short8*)(wb + WOFF(i * 6 + g));

  const float vbu = bu[n], vbr = br[n], vbh = bh[n];
  if (tid < 32) a_s[tid] = a[rowbase + tid];

  // ---- convert + write tiles in fragment order ----
  // element (r,k): slab=k>>4, slot=r|(((k>>3)&1)<<5), byte j=(k&7)*2
  // addr = (slab<<10) + ((slot^(slab&7))<<4) + j
#define TWRITE(DST, V, I)                                                   \
  {                                                                         \
    int f   = (I) * 256 + tid;                                              \
    int r   = f >> 6;                                                       \
    int k0  = (f & 63) << 2;                                                \
    int s_  = k0 >> 4;                                                      \
    int slt = r | (((k0 >> 3) & 1) << 5);                                   \
    ushort4 b;                                                              \
    b.x = f2bf(V[I].x); b.y = f2bf(V[I].y);                                 \
    b.z = f2bf(V[I].z); b.w = f2bf(V[I].w);                                 \
    *(ushort4*)((DST) + (s_ << 10) + ((slt ^ (s_ & 7)) << 4) +              \
                ((k0 & 7) << 1)) = b;                                       \
  }
#pragma unroll
  for (int i = 0; i < 8; ++i) TWRITE(lX, xv, i)
#pragma unroll
  for (int i = 0; i < 8; ++i) TWRITE(lH, hv, i)
  __syncthreads();

  f32x16 accU = {}, accR = {}, accXH = {}, accHH = {};

  // ---- merged K-loop: 16 slabs, 6 gates each. No barriers. ----
#pragma unroll
  for (int s = 0; s < 16; ++s) {
    const int toff = (s << 10) + ((l ^ (s & 7)) << 4);
    short8 ax = *(const short8*)(lX + toff);
    short8 ah = *(const short8*)(lH + toff);
    __builtin_amdgcn_s_setprio(1);
    accU  = MFMA32(ax, W[s % 3][0], accU, 0, 0, 0);
    accR  = MFMA32(ax, W[s % 3][1], accR, 0, 0, 0);
    accXH = MFMA32(ax, W[s % 3][2], accXH, 0, 0, 0);
    accU  = MFMA32(ah, W[s % 3][3], accU, 0, 0, 0);
    accR  = MFMA32(ah, W[s % 3][4], accR, 0, 0, 0);
    accHH = MFMA32(ah, W[s % 3][5], accHH, 0, 0, 0);
    __builtin_amdgcn_s_setprio(0);
    if (s + 3 < 16) {
      const int sg = (s + 3) * 6;
#pragma unroll
      for (int g = 0; g < 6; ++g)
        W[s % 3][g] = *(const short8*)(wb + WOFF(sg + g));
    }
  }

  // ---- epilogue: coalesced fp32 h1 re-read (L2-hot), gates, blend ----
  const float* hcol = h1 + rowbase * 256 + n;
  float* ocol = out + rowbase * 256 + n;
  float hE[16];
#pragma unroll
  for (int g8 = 0; g8 < 4; ++g8)
#pragma unroll
    for (int j = 0; j < 4; ++j) {
      const int rl = g8 * 8 + fq * 4 + j;
      hE[g8 * 4 + j] = hcol[(long)rl * 256];
    }

#pragma unroll
  for (int g8 = 0; g8 < 4; ++g8)
#pragma unroll
    for (int j = 0; j < 4; ++j) {
      const int reg = g8 * 4 + j;
      const int rl  = g8 * 8 + fq * 4 + j;        // C layout row
      const float pu = accU[reg] + vbu;
      const float pr = accR[reg] + vbr;
      const float uu = __builtin_amdgcn_rcpf(1.f + __expf(-pu));
      const float rr = __builtin_amdgcn_rcpf(1.f + __expf(-pr));
      const float cc = fmaf(rr, accHH[reg], accXH[reg]) + vbh;
      const float tt = __builtin_amdgcn_rcpf(1.f + __expf(-2.f * cc));
      const float th = fmaf(2.f, tt, -1.f);
      const float uh = a_s[rl] * uu;
      const float h1v = hE[reg];
      ocol[(long)rl * 256] = fmaf(uh, th - h1v, h1v);
    }
#undef TWRITE
#undef WOFF
}

extern "C" void kernel_launch(void* const* d_in, const int* in_sizes, int n_in,
                              void* d_out, int out_size, void* d_ws, size_t ws_size,
                              hipStream_t stream) {
  const float* x  = (const float*)d_in[0];
  const float* h1 = (const float*)d_in[1];
  const float* a  = (const float*)d_in[2];
  const float* Wu = (const float*)d_in[3];
  const float* Uu = (const float*)d_in[4];
  const float* bu = (const float*)d_in[5];
  const float* Wr = (const float*)d_in[6];
  const float* Ur = (const float*)d_in[7];
  const float* br = (const float*)d_in[8];
  const float* Wh = (const float*)d_in[9];
  const float* Uh = (const float*)d_in[10];
  const float* bh = (const float*)d_in[11];
  unsigned short* wt = (unsigned short*)d_ws;   // 16 slabs x 48 KB = 768 KB

  wprep<<<1536, 256, 0, stream>>>(Wu, Wr, Wh, Uu, Ur, Uh, wt);

  const int rows = in_sizes[0] / 256;           // 65536
  augru_main<<<(rows / 32) * 2, 256, 0, stream>>>(x, h1, a, wt, bu, br, bh,
                                                  (float*)d_out);
}